// Round 2
// baseline (2305.578 us; speedup 1.0000x reference)
//
#include <hip/hip_runtime.h>
#include <cstdint>
#include <cstddef>

#define NN 50000
#define EE 800000
#define CAP 64
#define EPS_BN 1e-5f

// ---------------- graph preprocessing ----------------

__global__ void k_outdeg(const int* __restrict__ row, int* __restrict__ outdeg){
  int e = blockIdx.x * blockDim.x + threadIdx.x;
  if (e < EE) atomicAdd(&outdeg[row[e]], 1);
}

__global__ void k_fill(const int* __restrict__ row, const int* __restrict__ col,
                       const int* __restrict__ outdeg,
                       int* __restrict__ incnt, int* __restrict__ bsrc,
                       float* __restrict__ bnorm){
  int e = blockIdx.x * blockDim.x + threadIdx.x;
  if (e >= EE) return;
  int r = row[e], c = col[e];
  int j = atomicAdd(&incnt[c], 1);
  if (j < CAP){
    bsrc[(size_t)c * CAP + j]  = r;
    bnorm[(size_t)c * CAP + j] = 1.0f / fmaxf((float)outdeg[r], 1.0f);
  }
}

// ---------------- aggregation: out[c] = sum_e w_e * hin[src_e]  ----------------
// wave per node; 16 lanes per source row (float4), 4 edges in flight.
// use_norm=1 -> w = bnorm (path step); use_norm=0 -> w = 1/max(cnt,1) (mean agg)

__global__ void __launch_bounds__(256) k_agg(const float* __restrict__ hin,
                                             float* __restrict__ out,
                                             const int* __restrict__ bsrc,
                                             const float* __restrict__ bnorm,
                                             const int* __restrict__ incnt,
                                             int use_norm){
  __shared__ int   sidx[4][CAP];
  __shared__ float swgt[4][CAP];
  int wib  = threadIdx.x >> 6;
  int lane = threadIdx.x & 63;
  int wid  = blockIdx.x * 4 + wib;
  bool valid = wid < NN;
  int cnt  = valid ? incnt[wid] : 0;
  int cntb = min(cnt, CAP);
  if (valid){
    int   si = (lane < cntb) ? bsrc[(size_t)wid * CAP + lane] : 0;
    float wv;
    if (use_norm) wv = (lane < cntb) ? bnorm[(size_t)wid * CAP + lane] : 0.f;
    else          wv = (lane < cntb) ? 1.0f / fmaxf((float)cnt, 1.f) : 0.f;
    sidx[wib][lane] = si;
    swgt[wib][lane] = wv;
  }
  __syncthreads();
  if (!valid) return;

  const float4* __restrict__ hin4 = (const float4*)hin;
  int g  = lane >> 4;     // edge slot within quad
  int fl = lane & 15;     // feature chunk (4 floats)
  float4 acc = {0.f, 0.f, 0.f, 0.f};
  for (int e0 = 0; e0 < cntb; e0 += 4){
    int e = e0 + g;
    int   s = sidx[wib][e];
    float w = swgt[wib][e];
    float4 v = hin4[(size_t)s * 16 + fl];
    acc.x = fmaf(w, v.x, acc.x);
    acc.y = fmaf(w, v.y, acc.y);
    acc.z = fmaf(w, v.z, acc.z);
    acc.w = fmaf(w, v.w, acc.w);
  }
  #pragma unroll
  for (int m = 16; m < 64; m <<= 1){
    acc.x += __shfl_xor(acc.x, m);
    acc.y += __shfl_xor(acc.y, m);
    acc.z += __shfl_xor(acc.z, m);
    acc.w += __shfl_xor(acc.w, m);
  }
  if (lane < 16) ((float4*)out)[(size_t)wid * 16 + fl] = acc;
}

// ---------------- dense ops ----------------

// out = X @ W (64x64) + b      (wave per node, lane = out feature)
__global__ void __launch_bounds__(256) k_gemm64(const float* __restrict__ X,
                                                const float* __restrict__ W,
                                                const float* __restrict__ bias,
                                                float* __restrict__ out){
  __shared__ float sW[4096];
  __shared__ float sb[64];
  for (int i = threadIdx.x; i < 4096; i += 256) sW[i] = W[i];
  if (threadIdx.x < 64) sb[threadIdx.x] = bias[threadIdx.x];
  __syncthreads();
  int lane = threadIdx.x & 63, wib = threadIdx.x >> 6;
  int stride = (blockDim.x >> 6) * gridDim.x;
  for (int n = blockIdx.x * (blockDim.x >> 6) + wib; n < NN; n += stride){
    float xv  = X[(size_t)n*64 + lane];
    float acc = sb[lane];
    #pragma unroll
    for (int k = 0; k < 64; ++k) acc = fmaf(__shfl(xv, k), sW[k*64 + lane], acc);
    out[(size_t)n*64 + lane] = acc;
  }
}

// h_out = relu(bn(mean@Wl + bl + h@Wr)) + h
__global__ void __launch_bounds__(256) k_sage(const float* __restrict__ h,
                                              const float* __restrict__ mean,
                                              const float* __restrict__ Wl,
                                              const float* __restrict__ bl,
                                              const float* __restrict__ Wr,
                                              const float* __restrict__ g,
                                              const float* __restrict__ be,
                                              const float* __restrict__ m,
                                              const float* __restrict__ var_,
                                              float* __restrict__ hout){
  __shared__ float sWl[4096], sWr[4096];
  __shared__ float ssc[64], ssh[64], sbl[64];
  for (int i = threadIdx.x; i < 4096; i += 256){ sWl[i] = Wl[i]; sWr[i] = Wr[i]; }
  if (threadIdx.x < 64){
    int f = threadIdx.x;
    float sc = g[f] * rsqrtf(var_[f] + EPS_BN);
    ssc[f] = sc; ssh[f] = be[f] - m[f] * sc; sbl[f] = bl[f];
  }
  __syncthreads();
  int lane = threadIdx.x & 63, wib = threadIdx.x >> 6;
  int stride = (blockDim.x >> 6) * gridDim.x;
  for (int n = blockIdx.x * (blockDim.x >> 6) + wib; n < NN; n += stride){
    float hv = h[(size_t)n*64 + lane];
    float mv = mean[(size_t)n*64 + lane];
    float acc = sbl[lane];
    #pragma unroll
    for (int k = 0; k < 64; ++k){
      acc = fmaf(__shfl(mv, k), sWl[k*64 + lane], acc);
      acc = fmaf(__shfl(hv, k), sWr[k*64 + lane], acc);
    }
    float t = fmaf(acc, ssc[lane], ssh[lane]);
    hout[(size_t)n*64 + lane] = fmaxf(t, 0.f) + hv;
  }
}

// [Y|R] = pieces(384) @ [vW_l|vW_r];  R gets +vb_l.   32 nodes per block.
__global__ void __launch_bounds__(256) k_gemm_YR(
    const float* __restrict__ x0, const float* __restrict__ x1, const float* __restrict__ x2,
    const float* __restrict__ x3, const float* __restrict__ x4, const float* __restrict__ x5,
    const float* __restrict__ WL, const float* __restrict__ WR, const float* __restrict__ vbl,
    float* __restrict__ Y, float* __restrict__ R){
  __shared__ float sWL[4096], sWR[4096];
  const float* X[6] = {x0, x1, x2, x3, x4, x5};
  int lane = threadIdx.x & 63, wib = threadIdx.x >> 6;
  int base = blockIdx.x * 32 + wib * 8;
  float accY[8] = {0,0,0,0,0,0,0,0};
  float accR[8] = {0,0,0,0,0,0,0,0};
  #pragma unroll
  for (int p = 0; p < 6; ++p){
    __syncthreads();
    for (int i = threadIdx.x; i < 4096; i += 256){ sWL[i] = WL[p*4096 + i]; sWR[i] = WR[p*4096 + i]; }
    __syncthreads();
    float xv[8];
    #pragma unroll
    for (int i = 0; i < 8; ++i) xv[i] = (base + i < NN) ? X[p][(size_t)(base+i)*64 + lane] : 0.f;
    #pragma unroll
    for (int k = 0; k < 64; ++k){
      float wl = sWL[k*64 + lane], wr = sWR[k*64 + lane];
      #pragma unroll
      for (int i = 0; i < 8; ++i){
        float xs = __shfl(xv[i], k);
        accY[i] = fmaf(xs, wl, accY[i]);
        accR[i] = fmaf(xs, wr, accR[i]);
      }
    }
  }
  float bias = vbl[lane];
  #pragma unroll
  for (int i = 0; i < 8; ++i){
    int n = base + i;
    if (n < NN){
      Y[(size_t)n*64 + lane] = accY[i];
      R[(size_t)n*64 + lane] = accR[i] + bias;
    }
  }
}

// v = relu(bn(Yagg + R)); mu = v@Wm + bm; lv = v@Wv + bv
__global__ void __launch_bounds__(256) k_mulv(const float* __restrict__ Yagg,
                                              const float* __restrict__ R,
                                              const float* __restrict__ g,
                                              const float* __restrict__ be,
                                              const float* __restrict__ m,
                                              const float* __restrict__ var_,
                                              const float* __restrict__ Wm,
                                              const float* __restrict__ bm,
                                              const float* __restrict__ Wv,
                                              const float* __restrict__ bv,
                                              float* __restrict__ mu, float* __restrict__ lv){
  __shared__ float sWm[4096], sWv[4096];
  __shared__ float sbm[64], sbv[64], ssc[64], ssh[64];
  for (int i = threadIdx.x; i < 4096; i += 256){ sWm[i] = Wm[i]; sWv[i] = Wv[i]; }
  if (threadIdx.x < 64){
    int f = threadIdx.x;
    float sc = g[f] * rsqrtf(var_[f] + EPS_BN);
    ssc[f] = sc; ssh[f] = be[f] - m[f] * sc;
    sbm[f] = bm[f]; sbv[f] = bv[f];
  }
  __syncthreads();
  int lane = threadIdx.x & 63, wib = threadIdx.x >> 6;
  int stride = (blockDim.x >> 6) * gridDim.x;
  for (int n = blockIdx.x * (blockDim.x >> 6) + wib; n < NN; n += stride){
    float t  = Yagg[(size_t)n*64 + lane] + R[(size_t)n*64 + lane];
    float vv = fmaxf(fmaf(t, ssc[lane], ssh[lane]), 0.f);
    float am = sbm[lane], al = sbv[lane];
    #pragma unroll
    for (int k = 0; k < 64; ++k){
      float s = __shfl(vv, k);
      am = fmaf(s, sWm[k*64 + lane], am);
      al = fmaf(s, sWv[k*64 + lane], al);
    }
    mu[(size_t)n*64 + lane] = am;
    lv[(size_t)n*64 + lane] = al;
  }
}

// rank = relu(mu@W1+b1) @ W2 + b2
__global__ void __launch_bounds__(256) k_rank(const float* __restrict__ mu,
                                              const float* __restrict__ W1,
                                              const float* __restrict__ b1,
                                              const float* __restrict__ W2,
                                              const float* __restrict__ b2,
                                              float* __restrict__ rout){
  __shared__ float sW[4096];
  __shared__ float sb1[64], sw2[64];
  for (int i = threadIdx.x; i < 4096; i += 256) sW[i] = W1[i];
  if (threadIdx.x < 64){ sb1[threadIdx.x] = b1[threadIdx.x]; sw2[threadIdx.x] = W2[threadIdx.x]; }
  __syncthreads();
  int lane = threadIdx.x & 63, wib = threadIdx.x >> 6;
  int stride = (blockDim.x >> 6) * gridDim.x;
  float b2v = b2[0];
  for (int n = blockIdx.x * (blockDim.x >> 6) + wib; n < NN; n += stride){
    float muv = mu[(size_t)n*64 + lane];
    float t = sb1[lane];
    #pragma unroll
    for (int k = 0; k < 64; ++k) t = fmaf(__shfl(muv, k), sW[k*64 + lane], t);
    t = fmaxf(t, 0.f);
    float val = t * sw2[lane];
    #pragma unroll
    for (int s = 32; s > 0; s >>= 1) val += __shfl_xor(val, s);
    if (lane == 0) rout[n] = val + b2v;
  }
}

// reg head: reg_in(385) -> 64 relu -> 32 relu -> 1
__global__ void __launch_bounds__(256) k_reg(
    const float* __restrict__ x0, const float* __restrict__ x1, const float* __restrict__ x2,
    const float* __restrict__ x3, const float* __restrict__ x4, const float* __restrict__ x5,
    const float* __restrict__ rank,
    const float* __restrict__ W1, const float* __restrict__ b1,
    const float* __restrict__ W2, const float* __restrict__ b2,
    const float* __restrict__ W3, const float* __restrict__ b3,
    float* __restrict__ preds){
  __shared__ float sW[4096];
  __shared__ float sW2[2048];
  __shared__ float sW3[32];
  const float* X[6] = {x0, x1, x2, x3, x4, x5};
  int lane = threadIdx.x & 63, wib = threadIdx.x >> 6;
  int base = blockIdx.x * 32 + wib * 8;
  for (int i = threadIdx.x; i < 2048; i += 256) sW2[i] = W2[i];
  if (threadIdx.x < 32) sW3[threadIdx.x] = W3[threadIdx.x];
  float acc[8] = {0,0,0,0,0,0,0,0};
  #pragma unroll
  for (int p = 0; p < 6; ++p){
    __syncthreads();
    for (int i = threadIdx.x; i < 4096; i += 256) sW[i] = W1[p*4096 + i];
    __syncthreads();
    float xv[8];
    #pragma unroll
    for (int i = 0; i < 8; ++i) xv[i] = (base + i < NN) ? X[p][(size_t)(base+i)*64 + lane] : 0.f;
    #pragma unroll
    for (int k = 0; k < 64; ++k){
      float wv = sW[k*64 + lane];
      #pragma unroll
      for (int i = 0; i < 8; ++i) acc[i] = fmaf(__shfl(xv[i], k), wv, acc[i]);
    }
  }
  float w384 = W1[4096*6 + lane];   // row 384 (rank_score)
  float b1v = b1[lane];
  int j = lane & 31;                // second layer: both wave halves duplicate j
  float b2v = b2[j];
  float b3v = b3[0];
  #pragma unroll
  for (int i = 0; i < 8; ++i){
    int n = base + i;
    if (n >= NN) continue;
    float a = fmaxf(acc[i] + b1v + rank[n] * w384, 0.f);  // h1 across lanes
    float part = 0.f;
    #pragma unroll
    for (int k = 0; k < 64; ++k)
      part = fmaf(__shfl(a, k), sW2[k*32 + j], part);      // constant k -> readlane
    float h2 = fmaxf(part + b2v, 0.f);
    float val = (lane < 32) ? h2 * sW3[j] : 0.f;
    #pragma unroll
    for (int s = 32; s > 0; s >>= 1) val += __shfl_xor(val, s);
    if (lane == 0) preds[n] = val + b3v;
  }
}

// ---------------- launch ----------------

extern "C" void kernel_launch(void* const* d_in, const int* in_sizes, int n_in,
                              void* d_out, int out_size, void* d_ws, size_t ws_size,
                              hipStream_t stream){
  const float* x    = (const float*)d_in[0];
  const int*   eidx = (const int*)d_in[1];
  const int* row = eidx;
  const int* col = eidx + EE;
  const float* W_in = (const float*)d_in[2];
  const float* b_in = (const float*)d_in[3];
  const float* sWl  = (const float*)d_in[4];
  const float* sbl  = (const float*)d_in[5];
  const float* sWr  = (const float*)d_in[6];
  const float* bng  = (const float*)d_in[7];
  const float* bnb  = (const float*)d_in[8];
  const float* bnm  = (const float*)d_in[9];
  const float* bnv  = (const float*)d_in[10];
  const float* vWl  = (const float*)d_in[11];
  const float* vbl  = (const float*)d_in[12];
  const float* vWr  = (const float*)d_in[13];
  const float* vg   = (const float*)d_in[14];
  const float* vbe  = (const float*)d_in[15];
  const float* vm   = (const float*)d_in[16];
  const float* vvar = (const float*)d_in[17];
  const float* Wmu  = (const float*)d_in[18];
  const float* bmu  = (const float*)d_in[19];
  const float* Wlv  = (const float*)d_in[20];
  const float* blv  = (const float*)d_in[21];
  const float* rW1  = (const float*)d_in[22];
  const float* rb1  = (const float*)d_in[23];
  const float* rW2  = (const float*)d_in[24];
  const float* rb2  = (const float*)d_in[25];
  const float* gW1  = (const float*)d_in[26];
  const float* gb1  = (const float*)d_in[27];
  const float* gW2  = (const float*)d_in[28];
  const float* gb2  = (const float*)d_in[29];
  const float* gW3  = (const float*)d_in[30];
  const float* gb3  = (const float*)d_in[31];

  float* preds = (float*)d_out;
  float* rank  = preds + NN;
  float* mu    = rank + NN;
  float* lv    = mu + (size_t)NN * 64;

  char* w = (char*)d_ws;
  auto alloc = [&](size_t bytes) -> char* {
    char* p = w; w += (bytes + 255) & ~(size_t)255; return p;
  };
  int*   outdeg = (int*)alloc((size_t)NN * 4);
  int*   incnt  = (int*)alloc((size_t)NN * 4);
  int*   bsrc   = (int*)alloc((size_t)NN * CAP * 4);
  float* bnorm  = (float*)alloc((size_t)NN * CAP * 4);
  float* skip   = (float*)alloc((size_t)NN * 64 * 4);
  float* hl[4];
  for (int i = 0; i < 4; ++i) hl[i] = (float*)alloc((size_t)NN * 64 * 4);
  float* meanb  = (float*)alloc((size_t)NN * 64 * 4);
  float* pa     = (float*)alloc((size_t)NN * 64 * 4);
  float* pb     = (float*)alloc((size_t)NN * 64 * 4);
  float* Yb     = (float*)alloc((size_t)NN * 64 * 4);
  float* Rb     = (float*)alloc((size_t)NN * 64 * 4);

  hipMemsetAsync(outdeg, 0, (size_t)NN * 4, stream);
  hipMemsetAsync(incnt,  0, (size_t)NN * 4, stream);

  const int EB = (EE + 255) / 256;
  k_outdeg<<<EB, 256, 0, stream>>>(row, outdeg);
  k_fill  <<<EB, 256, 0, stream>>>(row, col, outdeg, incnt, bsrc, bnorm);

  k_gemm64<<<1024, 256, 0, stream>>>(x, W_in, b_in, skip);

  const int AGG_B = (NN + 3) / 4;  // wave per node, 4 waves/block
  const float* hprev = x;
  for (int i = 0; i < 4; ++i){
    k_agg<<<AGG_B, 256, 0, stream>>>(hprev, meanb, bsrc, bnorm, incnt, 0);
    k_sage<<<1024, 256, 0, stream>>>(hprev, meanb, sWl + i*4096, sbl + i*64, sWr + i*4096,
                                     bng + i*64, bnb + i*64, bnm + i*64, bnv + i*64, hl[i]);
    hprev = hl[i];
  }

  k_agg<<<AGG_B, 256, 0, stream>>>(hl[3], pa, bsrc, bnorm, incnt, 1);
  k_agg<<<AGG_B, 256, 0, stream>>>(pa, pb, bsrc, bnorm, incnt, 1);
  k_agg<<<AGG_B, 256, 0, stream>>>(pb, pa, bsrc, bnorm, incnt, 1);
  k_agg<<<AGG_B, 256, 0, stream>>>(pa, pb, bsrc, bnorm, incnt, 1);
  // path_out = pb

  const int NB32 = (NN + 31) / 32;
  k_gemm_YR<<<NB32, 256, 0, stream>>>(hl[0], hl[1], hl[2], hl[3], skip, pb,
                                      vWl, vWr, vbl, Yb, Rb);
  k_agg<<<AGG_B, 256, 0, stream>>>(Yb, meanb, bsrc, bnorm, incnt, 0);   // mean of Y
  k_mulv<<<1024, 256, 0, stream>>>(meanb, Rb, vg, vbe, vm, vvar,
                                   Wmu, bmu, Wlv, blv, mu, lv);
  k_rank<<<1024, 256, 0, stream>>>(mu, rW1, rb1, rW2, rb2, rank);
  k_reg<<<NB32, 256, 0, stream>>>(hl[0], hl[1], hl[2], hl[3], skip, mu, rank,
                                  gW1, gb1, gW2, gb2, gW3, gb3, preds);
}

// Round 4
// 690.765 us; speedup vs baseline: 3.3377x; 3.3377x over previous
//
#include <hip/hip_runtime.h>
#include <cstdint>
#include <cstddef>

#define NN 50000
#define EE 800000
#define CAP 64
#define EPS_BN 1e-5f

typedef short  s16x8 __attribute__((ext_vector_type(8)));
typedef float  f32x4 __attribute__((ext_vector_type(4)));

#define MFMA16(a, b, c) __builtin_amdgcn_mfma_f32_16x16x32_bf16((a), (b), (c), 0, 0, 0)

__device__ inline ushort f2bf(float f){           // round-to-nearest-even fp32->bf16
  uint32_t u = __float_as_uint(f);
  uint32_t r = (u + 0x7FFFu + ((u >> 16) & 1u)) >> 16;
  return (ushort)r;
}

// ---------------- graph preprocessing ----------------

__global__ void k_outdeg(const int* __restrict__ row, int* __restrict__ outdeg){
  int e = blockIdx.x * blockDim.x + threadIdx.x;
  if (e < EE) atomicAdd(&outdeg[row[e]], 1);
}

__global__ void k_fill(const int* __restrict__ row, const int* __restrict__ col,
                       const int* __restrict__ outdeg,
                       int* __restrict__ incnt, int* __restrict__ bsrc,
                       float* __restrict__ bnorm){
  int e = blockIdx.x * blockDim.x + threadIdx.x;
  if (e >= EE) return;
  int r = row[e], c = col[e];
  int j = atomicAdd(&incnt[c], 1);
  if (j < CAP){
    bsrc[(size_t)c * CAP + j]  = r;
    bnorm[(size_t)c * CAP + j] = 1.0f / fmaxf((float)outdeg[r], 1.0f);
  }
}

// ---------------- weight conversion: fp32 [K x NF] -> bf16 [NF x dstK] (transposed) ----

struct ConvJob { const float* src; ushort* dst; int K; int shift; int mask; int koff; int dstK; };
struct ConvJobs { ConvJob j[16]; };

__global__ void k_conv(ConvJobs J){
  ConvJob jb = J.j[blockIdx.x];
  int total = jb.K << jb.shift;
  for (int idx = threadIdx.x; idx < total; idx += 256){
    int f = idx & jb.mask, k = idx >> jb.shift;
    jb.dst[(size_t)f * jb.dstK + jb.koff + k] = f2bf(jb.src[idx]);
  }
}

// ---------------- aggregation: out[c] = sum_e w_e * hin[src_e] ----------------

__global__ void __launch_bounds__(256) k_agg(const float* __restrict__ hin,
                                             float* __restrict__ out,
                                             const int* __restrict__ bsrc,
                                             const float* __restrict__ bnorm,
                                             const int* __restrict__ incnt,
                                             int use_norm){
  __shared__ int   sidx[4][CAP];
  __shared__ float swgt[4][CAP];
  int wib  = threadIdx.x >> 6;
  int lane = threadIdx.x & 63;
  int wid  = blockIdx.x * 4 + wib;
  bool valid = wid < NN;
  int cnt  = valid ? incnt[wid] : 0;
  int cntb = min(cnt, CAP);
  if (valid){
    int   si = (lane < cntb) ? bsrc[(size_t)wid * CAP + lane] : 0;
    float wv;
    if (use_norm) wv = (lane < cntb) ? bnorm[(size_t)wid * CAP + lane] : 0.f;
    else          wv = (lane < cntb) ? 1.0f / fmaxf((float)cnt, 1.f) : 0.f;
    sidx[wib][lane] = si;
    swgt[wib][lane] = wv;
  }
  __syncthreads();
  if (!valid) return;

  const float4* __restrict__ hin4 = (const float4*)hin;
  int g  = lane >> 4;
  int fl = lane & 15;
  float4 acc = {0.f, 0.f, 0.f, 0.f};
  for (int e0 = 0; e0 < cntb; e0 += 4){
    int e = e0 + g;
    int   s = sidx[wib][e];
    float w = swgt[wib][e];
    float4 v = hin4[(size_t)s * 16 + fl];
    acc.x = fmaf(w, v.x, acc.x);
    acc.y = fmaf(w, v.y, acc.y);
    acc.z = fmaf(w, v.z, acc.z);
    acc.w = fmaf(w, v.w, acc.w);
  }
  #pragma unroll
  for (int m = 16; m < 64; m <<= 1){
    acc.x += __shfl_xor(acc.x, m);
    acc.y += __shfl_xor(acc.y, m);
    acc.z += __shfl_xor(acc.z, m);
    acc.w += __shfl_xor(acc.w, m);
  }
  if (lane < 16) ((float4*)out)[(size_t)wid * 16 + fl] = acc;
}

// ---------------- MFMA GEMM machinery ----------------
// Block: 256 threads = 4 waves, 64 rows (16 per wave). LDS tile: 64 rows x 64 bf16,
// row stride 72 halfwords (144 B pad -> 2-way bank alias only).
// A-frag: row = lane&15, k = (lane>>4)*8+j.  B-frag: col = lane&15, same k, from WT[NF][K].
// C/D:   col = lane&15, row = (lane>>4)*4 + reg   [m89-verified]

__device__ inline void stage64(ushort* sX, const float* __restrict__ src, int base){
  int t = threadIdx.x;
  int rr = t >> 4, c4 = (t & 15) << 2;
  #pragma unroll
  for (int i = 0; i < 4; ++i){
    int r = rr + (i << 4);
    int n = base + r;
    float4 v = {0.f, 0.f, 0.f, 0.f};
    if (n < NN) v = *(const float4*)(src + (size_t)n * 64 + c4);
    ushort4 u;
    u.x = f2bf(v.x); u.y = f2bf(v.y); u.z = f2bf(v.z); u.w = f2bf(v.w);
    *(ushort4*)(sX + r * 72 + c4) = u;
  }
}

__device__ inline s16x8 loadA(const ushort* sX, int wrow, int ks, int q){
  return *(const s16x8*)(sX + wrow * 72 + ks * 32 + q * 8);
}

__device__ inline s16x8 loadB(const ushort* __restrict__ WT, int dstK, int col, int kidx){
  return *(const s16x8*)(WT + (size_t)col * dstK + kidx);
}

template<int P, int NCT>
__device__ inline void gemm_core(const float* const* pieces, const ushort* __restrict__ WT,
                                 int dstK, int base, ushort* sX, f32x4* acc){
  int lane = threadIdx.x & 63, wv = threadIdx.x >> 6;
  int q = lane >> 4, r16 = lane & 15;
  int wrow = wv * 16 + r16;
  #pragma unroll
  for (int p = 0; p < P; ++p){
    __syncthreads();
    stage64(sX, pieces[p], base);
    __syncthreads();
    #pragma unroll
    for (int ks = 0; ks < 2; ++ks){
      s16x8 a = loadA(sX, wrow, ks, q);
      #pragma unroll
      for (int ct = 0; ct < NCT; ++ct){
        s16x8 b = loadB(WT, dstK, ct * 16 + r16, p * 64 + ks * 32 + q * 8);
        acc[ct] = MFMA16(a, b, acc[ct]);
      }
    }
  }
}

// ---- skip = x @ W_in + b_in ----
__global__ void __launch_bounds__(256) k_skip(const float* __restrict__ x,
                                              const ushort* __restrict__ WT,
                                              const float* __restrict__ bias,
                                              float* __restrict__ out){
  __shared__ __align__(16) ushort sX[4608];
  const float* pieces[1] = {x};
  f32x4 acc[4] = {};
  int base = blockIdx.x * 64;
  gemm_core<1, 4>(pieces, WT, 64, base, sX, acc);
  int lane = threadIdx.x & 63, wv = threadIdx.x >> 6, q = lane >> 4, r16 = lane & 15;
  #pragma unroll
  for (int ct = 0; ct < 4; ++ct){
    int col = ct * 16 + r16;
    float b = bias[col];
    #pragma unroll
    for (int r = 0; r < 4; ++r){
      int row = base + wv * 16 + q * 4 + r;
      if (row < NN) out[(size_t)row * 64 + col] = acc[ct][r] + b;
    }
  }
}

// ---- sage layer: out = relu(bn([mean|h]@[Wl;Wr] + bl)) + h ----
__global__ void __launch_bounds__(256) k_sage_m(const float* __restrict__ meanb,
                                                const float* __restrict__ h,
                                                const ushort* __restrict__ WT,
                                                const float* __restrict__ bl,
                                                const float* __restrict__ g,
                                                const float* __restrict__ be,
                                                const float* __restrict__ m_,
                                                const float* __restrict__ var_,
                                                float* __restrict__ hout){
  __shared__ __align__(16) ushort sX[4608];
  const float* pieces[2] = {meanb, h};
  f32x4 acc[4] = {};
  int base = blockIdx.x * 64;
  gemm_core<2, 4>(pieces, WT, 128, base, sX, acc);
  int lane = threadIdx.x & 63, wv = threadIdx.x >> 6, q = lane >> 4, r16 = lane & 15;
  #pragma unroll
  for (int ct = 0; ct < 4; ++ct){
    int col = ct * 16 + r16;
    float sc = g[col] * rsqrtf(var_[col] + EPS_BN);
    float sh = be[col] - m_[col] * sc;
    float bb = bl[col];
    #pragma unroll
    for (int r = 0; r < 4; ++r){
      int row = base + wv * 16 + q * 4 + r;
      if (row < NN){
        float t = (acc[ct][r] + bb) * sc + sh;
        hout[(size_t)row * 64 + col] = fmaxf(t, 0.f) + h[(size_t)row * 64 + col];
      }
    }
  }
}

// ---- YR: [h1..h4|skip|path](384) @ [vWl|vWr] -> Y (no bias), R (+vbl) ----
__global__ void __launch_bounds__(256) k_yr(const float* __restrict__ x0, const float* __restrict__ x1,
                                            const float* __restrict__ x2, const float* __restrict__ x3,
                                            const float* __restrict__ x4, const float* __restrict__ x5,
                                            const ushort* __restrict__ WT, const float* __restrict__ vbl,
                                            float* __restrict__ Y, float* __restrict__ R){
  __shared__ __align__(16) ushort sX[4608];
  const float* pieces[6] = {x0, x1, x2, x3, x4, x5};
  f32x4 acc[8] = {};
  int base = blockIdx.x * 64;
  gemm_core<6, 8>(pieces, WT, 384, base, sX, acc);
  int lane = threadIdx.x & 63, wv = threadIdx.x >> 6, q = lane >> 4, r16 = lane & 15;
  #pragma unroll
  for (int ct = 0; ct < 8; ++ct){
    int col = ct * 16 + r16;
    bool isR = col >= 64;
    int c2 = isR ? (col - 64) : col;
    float b = isR ? vbl[c2] : 0.f;
    float* dst = isR ? R : Y;
    #pragma unroll
    for (int r = 0; r < 4; ++r){
      int row = base + wv * 16 + q * 4 + r;
      if (row < NN) dst[(size_t)row * 64 + c2] = acc[ct][r] + b;
    }
  }
}

// ---- mulv: v = relu(bn(Yagg+R)); [mu|lv] = v @ [Wmu|Wlv] + [bmu|blv] ----
__global__ void __launch_bounds__(256) k_mulv_m(const float* __restrict__ Yagg,
                                                const float* __restrict__ R,
                                                const float* __restrict__ vg,
                                                const float* __restrict__ vbe,
                                                const float* __restrict__ vm,
                                                const float* __restrict__ vvar,
                                                const ushort* __restrict__ WT,
                                                const float* __restrict__ bmu,
                                                const float* __restrict__ blv,
                                                float* __restrict__ mu, float* __restrict__ lv){
  __shared__ __align__(16) ushort sX[4608];
  __shared__ float ssc[64], ssh[64];
  int t = threadIdx.x;
  if (t < 64){
    float sc = vg[t] * rsqrtf(vvar[t] + EPS_BN);
    ssc[t] = sc; ssh[t] = vbe[t] - vm[t] * sc;
  }
  __syncthreads();
  int base = blockIdx.x * 64;
  int rr = t >> 4, c4 = (t & 15) << 2;
  #pragma unroll
  for (int i = 0; i < 4; ++i){
    int r = rr + (i << 4);
    int n = base + r;
    float4 a = {0,0,0,0}, b = {0,0,0,0};
    if (n < NN){
      a = *(const float4*)(Yagg + (size_t)n * 64 + c4);
      b = *(const float4*)(R    + (size_t)n * 64 + c4);
    }
    ushort4 u;
    u.x = f2bf(fmaxf((a.x + b.x) * ssc[c4+0] + ssh[c4+0], 0.f));
    u.y = f2bf(fmaxf((a.y + b.y) * ssc[c4+1] + ssh[c4+1], 0.f));
    u.z = f2bf(fmaxf((a.z + b.z) * ssc[c4+2] + ssh[c4+2], 0.f));
    u.w = f2bf(fmaxf((a.w + b.w) * ssc[c4+3] + ssh[c4+3], 0.f));
    *(ushort4*)(sX + r * 72 + c4) = u;
  }
  __syncthreads();
  int lane = t & 63, wv = t >> 6, q = lane >> 4, r16 = lane & 15;
  int wrow = wv * 16 + r16;
  f32x4 acc[8] = {};
  #pragma unroll
  for (int ks = 0; ks < 2; ++ks){
    s16x8 a = loadA(sX, wrow, ks, q);
    #pragma unroll
    for (int ct = 0; ct < 8; ++ct){
      s16x8 b = loadB(WT, 64, ct * 16 + r16, ks * 32 + q * 8);
      acc[ct] = MFMA16(a, b, acc[ct]);
    }
  }
  #pragma unroll
  for (int ct = 0; ct < 8; ++ct){
    int col = ct * 16 + r16;
    bool isL = col >= 64;
    int c2 = isL ? (col - 64) : col;
    float b = isL ? blv[c2] : bmu[c2];
    float* dst = isL ? lv : mu;
    #pragma unroll
    for (int r = 0; r < 4; ++r){
      int row = base + wv * 16 + q * 4 + r;
      if (row < NN) dst[(size_t)row * 64 + c2] = acc[ct][r] + b;
    }
  }
}

// ---- rank = relu(mu@rW1+rb1) @ rW2 + rb2 ----
__global__ void __launch_bounds__(256) k_rank_m(const float* __restrict__ muv,
                                                const ushort* __restrict__ WT,
                                                const float* __restrict__ rb1,
                                                const float* __restrict__ rW2,
                                                const float* __restrict__ rb2,
                                                float* __restrict__ rout){
  __shared__ __align__(16) ushort sX[4608];
  const float* pieces[1] = {muv};
  f32x4 acc[4] = {};
  int base = blockIdx.x * 64;
  gemm_core<1, 4>(pieces, WT, 64, base, sX, acc);
  int lane = threadIdx.x & 63, wv = threadIdx.x >> 6, q = lane >> 4, r16 = lane & 15;
  float val[4] = {0.f, 0.f, 0.f, 0.f};
  #pragma unroll
  for (int ct = 0; ct < 4; ++ct){
    int col = ct * 16 + r16;
    float b1 = rb1[col], w2 = rW2[col];
    #pragma unroll
    for (int r = 0; r < 4; ++r)
      val[r] += fmaxf(acc[ct][r] + b1, 0.f) * w2;
  }
  #pragma unroll
  for (int r = 0; r < 4; ++r){
    #pragma unroll
    for (int m = 1; m < 16; m <<= 1) val[r] += __shfl_xor(val[r], m);
  }
  if (r16 == 0){
    float b2 = rb2[0];
    #pragma unroll
    for (int r = 0; r < 4; ++r){
      int row = base + wv * 16 + q * 4 + r;
      if (row < NN) rout[row] = val[r] + b2;
    }
  }
}

// ---- reg stage 1: h1 = relu([stage1|z](384)@gW1[0:384] + gb1 + rank*gW1[384]) ----
__global__ void __launch_bounds__(256) k_reg1(const float* __restrict__ x0, const float* __restrict__ x1,
                                              const float* __restrict__ x2, const float* __restrict__ x3,
                                              const float* __restrict__ x4, const float* __restrict__ x5,
                                              const float* __restrict__ rank,
                                              const ushort* __restrict__ WT,
                                              const float* __restrict__ gW1,   // fp32, for row 384
                                              const float* __restrict__ gb1,
                                              float* __restrict__ h1buf){
  __shared__ __align__(16) ushort sX[4608];
  const float* pieces[6] = {x0, x1, x2, x3, x4, x5};
  f32x4 acc[4] = {};
  int base = blockIdx.x * 64;
  gemm_core<6, 4>(pieces, WT, 384, base, sX, acc);
  int lane = threadIdx.x & 63, wv = threadIdx.x >> 6, q = lane >> 4, r16 = lane & 15;
  float rk[4];
  #pragma unroll
  for (int r = 0; r < 4; ++r){
    int row = base + wv * 16 + q * 4 + r;
    rk[r] = (row < NN) ? rank[row] : 0.f;
  }
  #pragma unroll
  for (int ct = 0; ct < 4; ++ct){
    int col = ct * 16 + r16;
    float b1 = gb1[col];
    float w384 = gW1[384 * 64 + col];
    #pragma unroll
    for (int r = 0; r < 4; ++r){
      int row = base + wv * 16 + q * 4 + r;
      if (row < NN)
        h1buf[(size_t)row * 64 + col] = fmaxf(acc[ct][r] + b1 + rk[r] * w384, 0.f);
    }
  }
}

// ---- reg tail: h2 = relu(h1@gW2+gb2); preds = h2@gW3 + gb3 ----
__global__ void __launch_bounds__(256) k_reg2(const float* __restrict__ h1buf,
                                              const ushort* __restrict__ WT,
                                              const float* __restrict__ gb2,
                                              const float* __restrict__ gW3,
                                              const float* __restrict__ gb3,
                                              float* __restrict__ preds){
  __shared__ __align__(16) ushort sX[4608];
  const float* pieces[1] = {h1buf};
  f32x4 acc[2] = {};
  int base = blockIdx.x * 64;
  gemm_core<1, 2>(pieces, WT, 64, base, sX, acc);
  int lane = threadIdx.x & 63, wv = threadIdx.x >> 6, q = lane >> 4, r16 = lane & 15;
  float val[4] = {0.f, 0.f, 0.f, 0.f};
  #pragma unroll
  for (int ct = 0; ct < 2; ++ct){
    int col = ct * 16 + r16;       // 0..31
    float b2 = gb2[col], w3 = gW3[col];
    #pragma unroll
    for (int r = 0; r < 4; ++r)
      val[r] += fmaxf(acc[ct][r] + b2, 0.f) * w3;
  }
  #pragma unroll
  for (int r = 0; r < 4; ++r){
    #pragma unroll
    for (int m = 1; m < 16; m <<= 1) val[r] += __shfl_xor(val[r], m);
  }
  if (r16 == 0){
    float b3 = gb3[0];
    #pragma unroll
    for (int r = 0; r < 4; ++r){
      int row = base + wv * 16 + q * 4 + r;
      if (row < NN) preds[row] = val[r] + b3;
    }
  }
}

// ---------------- launch ----------------

extern "C" void kernel_launch(void* const* d_in, const int* in_sizes, int n_in,
                              void* d_out, int out_size, void* d_ws, size_t ws_size,
                              hipStream_t stream){
  const float* x    = (const float*)d_in[0];
  const int*   eidx = (const int*)d_in[1];
  const int* row = eidx;
  const int* col = eidx + EE;
  const float* W_in = (const float*)d_in[2];
  const float* b_in = (const float*)d_in[3];
  const float* sWl  = (const float*)d_in[4];
  const float* sbl  = (const float*)d_in[5];
  const float* sWr  = (const float*)d_in[6];
  const float* bng  = (const float*)d_in[7];
  const float* bnb  = (const float*)d_in[8];
  const float* bnm  = (const float*)d_in[9];
  const float* bnv  = (const float*)d_in[10];
  const float* vWl  = (const float*)d_in[11];
  const float* vbl  = (const float*)d_in[12];
  const float* vWr  = (const float*)d_in[13];
  const float* vg   = (const float*)d_in[14];
  const float* vbe  = (const float*)d_in[15];
  const float* vm   = (const float*)d_in[16];
  const float* vvar = (const float*)d_in[17];
  const float* Wmu  = (const float*)d_in[18];
  const float* bmu  = (const float*)d_in[19];
  const float* Wlv  = (const float*)d_in[20];
  const float* blv  = (const float*)d_in[21];
  const float* rW1  = (const float*)d_in[22];
  const float* rb1  = (const float*)d_in[23];
  const float* rW2  = (const float*)d_in[24];
  const float* rb2  = (const float*)d_in[25];
  const float* gW1  = (const float*)d_in[26];
  const float* gb1  = (const float*)d_in[27];
  const float* gW2  = (const float*)d_in[28];
  const float* gb2  = (const float*)d_in[29];
  const float* gW3  = (const float*)d_in[30];
  const float* gb3  = (const float*)d_in[31];

  float* preds = (float*)d_out;
  float* rank  = preds + NN;
  float* mu    = rank + NN;
  float* lv    = mu + (size_t)NN * 64;

  char* w = (char*)d_ws;
  auto alloc = [&](size_t bytes) -> char* {
    char* p = w; w += (bytes + 255) & ~(size_t)255; return p;
  };
  int*   outdeg = (int*)alloc((size_t)NN * 4);
  int*   incnt  = (int*)alloc((size_t)NN * 4);
  int*   bsrc   = (int*)alloc((size_t)NN * CAP * 4);
  float* bnorm  = (float*)alloc((size_t)NN * CAP * 4);
  float* skip   = (float*)alloc((size_t)NN * 64 * 4);
  float* hl[4];
  for (int i = 0; i < 4; ++i) hl[i] = (float*)alloc((size_t)NN * 64 * 4);
  float* meanb  = (float*)alloc((size_t)NN * 64 * 4);
  float* pa     = (float*)alloc((size_t)NN * 64 * 4);   // also reused as h1buf
  float* pb     = (float*)alloc((size_t)NN * 64 * 4);
  float* Yb     = (float*)alloc((size_t)NN * 64 * 4);
  float* Rb     = (float*)alloc((size_t)NN * 64 * 4);
  ushort* skipW = (ushort*)alloc(64 * 64 * 2);
  ushort* sageW = (ushort*)alloc(4 * 64 * 128 * 2);
  ushort* yrW   = (ushort*)alloc(128 * 384 * 2);
  ushort* mulvW = (ushort*)alloc(128 * 64 * 2);
  ushort* rankW = (ushort*)alloc(64 * 64 * 2);
  ushort* regW1 = (ushort*)alloc(64 * 384 * 2);
  ushort* regW2 = (ushort*)alloc(32 * 64 * 2);

  hipMemsetAsync(outdeg, 0, (size_t)NN * 4, stream);
  hipMemsetAsync(incnt,  0, (size_t)NN * 4, stream);

  const int EB = (EE + 255) / 256;
  k_outdeg<<<EB, 256, 0, stream>>>(row, outdeg);
  k_fill  <<<EB, 256, 0, stream>>>(row, col, outdeg, incnt, bsrc, bnorm);

  // weight conversions (16 jobs, 1 block each)
  ConvJobs J;
  auto job = [&](int i, const float* s, ushort* d, int K, int shift, int koff, int dstK){
    J.j[i] = {s, d, K, shift, (1 << shift) - 1, koff, dstK};
  };
  job(0,  W_in, skipW, 64, 6, 0, 64);
  for (int i = 0; i < 4; ++i){
    job(1 + i, sWl + i * 4096, sageW + i * 8192, 64, 6, 0,  128);
    job(5 + i, sWr + i * 4096, sageW + i * 8192, 64, 6, 64, 128);
  }
  job(9,  vWl, yrW,            384, 6, 0, 384);
  job(10, vWr, yrW + 64 * 384, 384, 6, 0, 384);
  job(11, Wmu, mulvW,           64, 6, 0, 64);
  job(12, Wlv, mulvW + 64 * 64, 64, 6, 0, 64);
  job(13, rW1, rankW,           64, 6, 0, 64);
  job(14, gW1, regW1,          384, 6, 0, 384);
  job(15, gW2, regW2,           64, 5, 0, 64);
  k_conv<<<16, 256, 0, stream>>>(J);

  const int GB = (NN + 63) / 64;   // 782 row-tile blocks
  k_skip<<<GB, 256, 0, stream>>>(x, skipW, b_in, skip);

  const int AGG_B = (NN + 3) / 4;
  const float* hprev = x;
  for (int i = 0; i < 4; ++i){
    k_agg<<<AGG_B, 256, 0, stream>>>(hprev, meanb, bsrc, bnorm, incnt, 0);
    k_sage_m<<<GB, 256, 0, stream>>>(meanb, hprev, sageW + i * 8192, sbl + i * 64,
                                     bng + i * 64, bnb + i * 64, bnm + i * 64, bnv + i * 64, hl[i]);
    hprev = hl[i];
  }

  k_agg<<<AGG_B, 256, 0, stream>>>(hl[3], pa, bsrc, bnorm, incnt, 1);
  k_agg<<<AGG_B, 256, 0, stream>>>(pa, pb, bsrc, bnorm, incnt, 1);
  k_agg<<<AGG_B, 256, 0, stream>>>(pb, pa, bsrc, bnorm, incnt, 1);
  k_agg<<<AGG_B, 256, 0, stream>>>(pa, pb, bsrc, bnorm, incnt, 1);
  // path_out = pb

  k_yr<<<GB, 256, 0, stream>>>(hl[0], hl[1], hl[2], hl[3], skip, pb, yrW, vbl, Yb, Rb);
  k_agg<<<AGG_B, 256, 0, stream>>>(Yb, meanb, bsrc, bnorm, incnt, 0);
  k_mulv_m<<<GB, 256, 0, stream>>>(meanb, Rb, vg, vbe, vm, vvar, mulvW, bmu, blv, mu, lv);
  k_rank_m<<<GB, 256, 0, stream>>>(mu, rankW, rb1, rW2, rb2, rank);
  k_reg1<<<GB, 256, 0, stream>>>(hl[0], hl[1], hl[2], hl[3], skip, mu, rank,
                                 regW1, gW1, gb1, pa);
  k_reg2<<<GB, 256, 0, stream>>>(pa, regW2, gb2, gW3, gb3, preds);
}